// Round 3
// baseline (350.614 us; speedup 1.0000x reference)
//
#include <hip/hip_runtime.h>

typedef __attribute__((ext_vector_type(8))) short short8;
typedef __attribute__((ext_vector_type(4))) float floatx4;

__device__ inline unsigned short f2bf(float f) {
    unsigned u = __float_as_uint(f);
    u += 0x7fffu + ((u >> 16) & 1u);   // round-to-nearest-even
    return (unsigned short)(u >> 16);
}

// 512-node chunks: chunk = tgt>>9, 98 chunks for N=50000.
// packed word: (chunk<<25) | (src<<9) | (tgt&511)   [src < 65536]
#define CHUNK_CAP 12288   // mean E/98 = 8163, sigma ~90
#define BTILE 2048        // split tiles: shorter serial chain, 2x parallelism
#define NPREP 256         // 4*16384/256 weight-convert blocks

// ============ K1: bin | csr(spin-wait) | weight prep | layer-0 GEMM ============
// Block ranges (dispatch order matters for the software barrier):
//   [0, ntilesE)                      edge binning (2048-edge tiles)
//   [ntilesE, ntilesE+nchunk)         CSR finalize — spins until all bins done
//   [.., +NPREP)                      weight fp32->bf16 prep (independent)
//   rest                              layer-0 GEMM, x0 built in-register
// Deadlock-free: all bin bids < all csr bids; 391+98 < 4 blocks/CU * 256 CU.

__global__ __launch_bounds__(256, 4) void front_fused(
    const float* __restrict__ attr, const float* __restrict__ cc,
    const float* __restrict__ bl, const float* __restrict__ ex,
    const float* __restrict__ Wf, const float* __restrict__ bias0,
    unsigned short* __restrict__ x1,
    const int* __restrict__ e, int* __restrict__ cursor, int* __restrict__ done,
    unsigned* __restrict__ packed_out,
    uint2* __restrict__ rows2, int* __restrict__ colv,
    const float* __restrict__ w1s, const float* __restrict__ w1n,
    const float* __restrict__ w2s, const float* __restrict__ w2n,
    const float* __restrict__ b1s, const float* __restrict__ b1n,
    const float* __restrict__ b2s, const float* __restrict__ b2n,
    unsigned short* __restrict__ wb, float* __restrict__ biasf,
    int N, int ATTR, int E, int ntilesE, int nchunk) {
    __shared__ __align__(16) char smem[18432];
    int t = threadIdx.x;
    int bid = blockIdx.x;

    if (bid < ntilesE) {
        // ---- edge binning: one 2048-edge tile into 128 chunk bins ----
        unsigned* buf  = (unsigned*)smem;                  // 8KB
        unsigned* sbuf = buf + BTILE;                      // 8KB
        int* hist  = (int*)(sbuf + BTILE);
        int* offs  = hist + 128;
        int* gbase = offs + 128;
        int* lcur  = gbase + 128;
        int e0 = bid * BTILE;
        int cnt = min(BTILE, E - e0);
        if (t < 128) hist[t] = 0;
        __syncthreads();
        for (int j = t; j < cnt; j += 256) {
            unsigned src = (unsigned)e[e0 + j];
            unsigned tgt = (unsigned)e[E + e0 + j];
            unsigned c = tgt >> 9;
            buf[j] = (c << 25) | (src << 9) | (tgt & 511u);
            atomicAdd(&hist[c], 1);
        }
        __syncthreads();
        if (t < 128) offs[t] = hist[t];
        __syncthreads();
        for (int o = 1; o < 128; o <<= 1) {
            int v = (t < 128 && t >= o) ? offs[t - o] : 0;
            __syncthreads();
            if (t < 128) offs[t] += v;
            __syncthreads();
        }
        if (t < 128) {
            int excl = offs[t] - hist[t];
            offs[t] = excl;
            lcur[t] = excl;
            gbase[t] = (hist[t] > 0) ? t * CHUNK_CAP + atomicAdd(&cursor[t], hist[t]) : 0;
        }
        __syncthreads();
        for (int j = t; j < cnt; j += 256) {
            unsigned v = buf[j];
            int c = v >> 25;
            int p = atomicAdd(&lcur[c], 1);
            sbuf[p] = v;
        }
        __syncthreads();
        // flat write-out: consecutive j -> mostly consecutive destinations
        for (int j = t; j < cnt; j += 256) {
            unsigned v = sbuf[j];
            int c = v >> 25;
            packed_out[gbase[c] + (j - offs[c])] = v;
        }
        __threadfence();            // make packed/cursor visible device-wide
        __syncthreads();
        if (t == 0) atomicAdd(done, 1);
        return;
    }

    if (bid < ntilesE + nchunk) {
        // ---- CSR finalize for one 512-node chunk (waits for all bins) ----
        int* hist = (int*)smem;       // 512
        int* offs = hist + 512;       // 512
        int* lcnt = offs + 512;       // 512
        int* pp   = lcnt + 512;       // 256
        int c = bid - ntilesE;
        if (t == 0) {
            while (atomicAdd(done, 0) < ntilesE) __builtin_amdgcn_s_sleep(8);
            __threadfence();          // acquire: invalidate before reading packed
        }
        __syncthreads();
        int base = c * CHUNK_CAP;
        int cnt = atomicAdd(&cursor[c], 0);
        hist[t] = 0;
        hist[t + 256] = 0;
        __syncthreads();
        for (int j = t; j < cnt; j += 256)
            atomicAdd(&hist[packed_out[base + j] & 511u], 1);
        __syncthreads();
        int a0 = hist[2 * t], a1 = hist[2 * t + 1];
        pp[t] = a0 + a1;
        __syncthreads();
        for (int o = 1; o < 256; o <<= 1) {
            int v = (t >= o) ? pp[t - o] : 0;
            __syncthreads();
            pp[t] += v;
            __syncthreads();
        }
        int excl = pp[t] - (a0 + a1);
        offs[2 * t] = excl;
        offs[2 * t + 1] = excl + a0;
        lcnt[2 * t] = 0;
        lcnt[2 * t + 1] = 0;
        __syncthreads();
        for (int j = t; j < 512; j += 256) {
            int node = c * 512 + j;
            if (node < N) {
                uint2 r;
                r.x = base + offs[j];
                r.y = base + offs[j] + hist[j];
                rows2[node] = r;
            }
        }
        // direct scattered colv write (L2-resident region, no LDS staging)
        for (int j = t; j < cnt; j += 256) {
            unsigned v = packed_out[base + j];
            int node = v & 511u;
            int p = offs[node] + atomicAdd(&lcnt[node], 1);
            colv[base + p] = (v >> 9) & 0xFFFFu;
        }
        return;
    }

    if (bid < ntilesE + nchunk + NPREP) {
        // ---- weight prep: w1s|w1n|w2s|w2n -> bf16, fused biases ----
        int pb = bid - ntilesE - nchunk;
        int idx = pb * 256 + t;            // 0..65535
        int m = idx >> 14, j = idx & 16383;
        const float* src = (m == 0) ? w1s : (m == 1) ? w1n : (m == 2) ? w2s : w2n;
        wb[idx] = f2bf(src[j]);
        if (pb == 0 && t < 128) {
            biasf[t]       = b1s[t] + b1n[t];
            biasf[128 + t] = b2s[t] + b2n[t];
        }
        return;
    }

    // ---- layer-0 GEMM: x1 = relu(x0 @ W_in^T + b_in), x0 built in-register ----
    // NOTE: assumes IN = ATTR+3 = 128 (fixed for this problem).
    unsigned short* lx = (unsigned short*)smem;   // 64 x 136 bf16 tile
    int lane = t & 63;
    int w = t >> 6;
    int node0 = (bid - ntilesE - nchunk - NPREP) * 64;
    int n_off = w * 32;
    int q = lane >> 4;
    int m16 = lane & 15;

    // B fragments: fp32 W_in -> bf16 in-register (L2-resident after first wave)
    short8 bf[2][4];
    #pragma unroll
    for (int nt = 0; nt < 2; ++nt)
        #pragma unroll
        for (int kk = 0; kk < 4; ++kk) {
            const float* p = Wf + (n_off + nt * 16 + m16) * 128 + kk * 32 + q * 8;
            float4 aa = *(const float4*)p, bb = *(const float4*)(p + 4);
            short8 r;
            r[0] = (short)f2bf(aa.x); r[1] = (short)f2bf(aa.y);
            r[2] = (short)f2bf(aa.z); r[3] = (short)f2bf(aa.w);
            r[4] = (short)f2bf(bb.x); r[5] = (short)f2bf(bb.y);
            r[6] = (short)f2bf(bb.z); r[7] = (short)f2bf(bb.w);
            bf[nt][kk] = r;
        }

    floatx4 acc[4][2];
    #pragma unroll
    for (int nt = 0; nt < 2; ++nt) {
        float bv = bias0[n_off + nt * 16 + m16];
        floatx4 b4 = {bv, bv, bv, bv};
        #pragma unroll
        for (int mt = 0; mt < 4; ++mt) acc[mt][nt] = b4;
    }

    if (node0 + 64 > N) {   // tail block: zero the tile first
        for (int i = t; i < 64 * 136; i += 256) lx[i] = 0;
        __syncthreads();
    }

    // attr -> bf16 tile, direct (thread = (row, 4-col group)); unaligned f4 ok
    #pragma unroll
    for (int i = 0; i < 8; ++i) {
        int idx = t + 256 * i;            // 64 rows x 32 groups
        int nd = idx >> 5, g = idx & 31;
        int row = node0 + nd;
        int c0 = g * 4;
        if (row < N && c0 < ATTR) {
            if (c0 + 3 < ATTR) {
                float4 f = *(const float4*)(attr + (size_t)row * ATTR + c0);
                unsigned lo = (unsigned)f2bf(f.x) | ((unsigned)f2bf(f.y) << 16);
                unsigned hi = (unsigned)f2bf(f.z) | ((unsigned)f2bf(f.w) << 16);
                uint2 pk; pk.x = lo; pk.y = hi;
                *(uint2*)(lx + nd * 136 + c0) = pk;
            } else {
                for (int k = 0; k < 4; ++k) {
                    int cidx = c0 + k;
                    if (cidx < ATTR) lx[nd * 136 + cidx] = f2bf(attr[(size_t)row * ATTR + cidx]);
                }
            }
        }
    }
    // boundary cols ATTR..ATTR+2 from cc/bl/ex
    {
        int nd = t >> 2, ci = t & 3;
        int row = node0 + nd;
        if (ci < 3 && row < N) {
            float v = (ci == 0) ? cc[row] : (ci == 1) ? bl[row] : ex[row];
            lx[nd * 136 + ATTR + ci] = f2bf(v);
        }
    }
    __syncthreads();

    #pragma unroll
    for (int kk = 0; kk < 4; ++kk) {
        short8 a[4];
        #pragma unroll
        for (int mt = 0; mt < 4; ++mt)
            a[mt] = *(const short8*)(lx + (mt * 16 + m16) * 136 + kk * 32 + q * 8);
        #pragma unroll
        for (int mt = 0; mt < 4; ++mt) {
            acc[mt][0] = __builtin_amdgcn_mfma_f32_16x16x32_bf16(a[mt], bf[0][kk], acc[mt][0], 0, 0, 0);
            acc[mt][1] = __builtin_amdgcn_mfma_f32_16x16x32_bf16(a[mt], bf[1][kk], acc[mt][1], 0, 0, 0);
        }
    }

    // epilogue: relu -> restage in LDS -> coalesced uint4 stores
    __syncthreads();
    #pragma unroll
    for (int mt = 0; mt < 4; ++mt)
        #pragma unroll
        for (int r = 0; r < 4; ++r) {
            int rl = mt * 16 + q * 4 + r;
            #pragma unroll
            for (int nt = 0; nt < 2; ++nt)
                lx[rl * 136 + n_off + nt * 16 + m16] = f2bf(fmaxf(acc[mt][nt][r], 0.0f));
        }
    __syncthreads();
    #pragma unroll
    for (int i = 0; i < 4; ++i) {
        int cidx = t + 256 * i;           // 64 rows x 16 chunks of 16B
        int nd = cidx >> 4, k = cidx & 15;
        int rr = node0 + nd;
        if (rr < N)
            *(uint4*)(x1 + (size_t)rr * 128 + k * 8) = *(const uint4*)(lx + nd * 136 + k * 8);
    }
}

// ============ fused SAGE layer: gather-mean + 2-phase GEMM + epilogue ============
// out = act(X @ W0^T + mean_neigh(X) @ W1^T + bias) [* ex]
// Per 64-node block: lxA = self tile, lxB = neighbor-mean tile (built by the
// proven one-wave-per-node volley gather, 16 nodes per wave), then MFMA.

__global__ __launch_bounds__(256, 3) void gemm_sage(
    const unsigned short* __restrict__ X,
    const uint2* __restrict__ rows2, const int* __restrict__ colv,
    const unsigned short* __restrict__ W0, const unsigned short* __restrict__ W1,
    const float* __restrict__ bias, const float* __restrict__ ex,
    unsigned short* __restrict__ obf, float* __restrict__ of32,
    int N, int relu) {
    __shared__ __align__(16) char smem[34816];
    unsigned short* lxA = (unsigned short*)smem;        // 64 x 136 self
    unsigned short* lxB = lxA + 64 * 136;               // 64 x 136 neigh-mean
    int t = threadIdx.x;
    int lane = t & 63;
    int w = t >> 6;
    int node0 = blockIdx.x * 64;
    int n_off = w * 32;
    int q = lane >> 4;
    int m16 = lane & 15;

    // B fragments (bf16, prep'd)
    short8 bf0[2][4], bf1[2][4];
    #pragma unroll
    for (int nt = 0; nt < 2; ++nt)
        #pragma unroll
        for (int kk = 0; kk < 4; ++kk) {
            bf0[nt][kk] = *(const short8*)(W0 + (n_off + nt * 16 + m16) * 128 + kk * 32 + q * 8);
            bf1[nt][kk] = *(const short8*)(W1 + (n_off + nt * 16 + m16) * 128 + kk * 32 + q * 8);
        }

    floatx4 acc[4][2];
    #pragma unroll
    for (int nt = 0; nt < 2; ++nt) {
        float bv = bias[n_off + nt * 16 + m16];
        floatx4 b4 = {bv, bv, bv, bv};
        #pragma unroll
        for (int mt = 0; mt < 4; ++mt) acc[mt][nt] = b4;
    }

    // stage self tile
    #pragma unroll
    for (int i = 0; i < 4; ++i) {
        int c = t + 256 * i;
        int nd = c >> 4, ck = c & 15;
        short8 v = {0, 0, 0, 0, 0, 0, 0, 0};
        if (node0 + nd < N) v = *(const short8*)(X + (size_t)(node0 + nd) * 128 + ck * 8);
        *(short8*)(lxA + nd * 136 + ck * 8) = v;
    }

    // gather-mean: wave w handles rows w*16 .. w*16+15
    int cl = m16 * 8;
    for (int i = 0; i < 16; ++i) {
        int row = w * 16 + i;
        int node = node0 + row;
        int s0 = 0, s1 = 0;
        if (node < N) { uint2 r2 = rows2[node]; s0 = r2.x; s1 = r2.y; }
        int deg = s1 - s0;
        int mn = deg < 64 ? deg : 64;
        int cvec = (lane < mn) ? colv[s0 + lane] : 0;
        float a0 = 0.f, a1 = 0.f, a2 = 0.f, a3 = 0.f;
        float a4 = 0.f, a5 = 0.f, a6 = 0.f, a7 = 0.f;
        int lim = mn - 1;
        for (int j = 0; j < mn; j += 32) {
            uint4 v[8];
            #pragma unroll
            for (int u = 0; u < 8; ++u) {
                int ei = j + 4 * u + q;
                int idx = (ei <= lim) ? ei : lim;    // clamp: dup loads hit cache
                int s = __shfl(cvec, idx, 64);
                v[u] = *(const uint4*)(X + (size_t)s * 128 + cl);
            }
            #pragma unroll
            for (int u = 0; u < 8; ++u) {
                int ei = j + 4 * u + q;
                if (ei <= lim) {
                    a0 += __uint_as_float(v[u].x << 16);
                    a1 += __uint_as_float(v[u].x & 0xffff0000u);
                    a2 += __uint_as_float(v[u].y << 16);
                    a3 += __uint_as_float(v[u].y & 0xffff0000u);
                    a4 += __uint_as_float(v[u].z << 16);
                    a5 += __uint_as_float(v[u].z & 0xffff0000u);
                    a6 += __uint_as_float(v[u].w << 16);
                    a7 += __uint_as_float(v[u].w & 0xffff0000u);
                }
            }
        }
        for (int eo = s0 + 64; eo < s1; eo += 4) {   // rare: deg > 64
            int ei = eo + q;
            int idx = (ei < s1) ? ei : s1 - 1;
            int s = colv[idx];
            uint4 v = *(const uint4*)(X + (size_t)s * 128 + cl);
            if (ei < s1) {
                a0 += __uint_as_float(v.x << 16);
                a1 += __uint_as_float(v.x & 0xffff0000u);
                a2 += __uint_as_float(v.y << 16);
                a3 += __uint_as_float(v.y & 0xffff0000u);
                a4 += __uint_as_float(v.z << 16);
                a5 += __uint_as_float(v.z & 0xffff0000u);
                a6 += __uint_as_float(v.w << 16);
                a7 += __uint_as_float(v.w & 0xffff0000u);
            }
        }
        a0 += __shfl_xor(a0, 16, 64); a0 += __shfl_xor(a0, 32, 64);
        a1 += __shfl_xor(a1, 16, 64); a1 += __shfl_xor(a1, 32, 64);
        a2 += __shfl_xor(a2, 16, 64); a2 += __shfl_xor(a2, 32, 64);
        a3 += __shfl_xor(a3, 16, 64); a3 += __shfl_xor(a3, 32, 64);
        a4 += __shfl_xor(a4, 16, 64); a4 += __shfl_xor(a4, 32, 64);
        a5 += __shfl_xor(a5, 16, 64); a5 += __shfl_xor(a5, 32, 64);
        a6 += __shfl_xor(a6, 16, 64); a6 += __shfl_xor(a6, 32, 64);
        a7 += __shfl_xor(a7, 16, 64); a7 += __shfl_xor(a7, 32, 64);
        if (q == 0) {
            float inv = 1.0f / (float)(deg > 1 ? deg : 1);
            a0 *= inv; a1 *= inv; a2 *= inv; a3 *= inv;
            a4 *= inv; a5 *= inv; a6 *= inv; a7 *= inv;
            uint4 o;
            o.x = ((unsigned)f2bf(a1) << 16) | (unsigned)f2bf(a0);
            o.y = ((unsigned)f2bf(a3) << 16) | (unsigned)f2bf(a2);
            o.z = ((unsigned)f2bf(a5) << 16) | (unsigned)f2bf(a4);
            o.w = ((unsigned)f2bf(a7) << 16) | (unsigned)f2bf(a6);
            *(uint4*)(lxB + row * 136 + cl) = o;
        }
    }
    __syncthreads();

    // MFMA: phase 0 = self x W0, phase 1 = neigh-mean x W1
    #pragma unroll
    for (int kk = 0; kk < 4; ++kk) {
        short8 a[4];
        #pragma unroll
        for (int mt = 0; mt < 4; ++mt)
            a[mt] = *(const short8*)(lxA + (mt * 16 + m16) * 136 + kk * 32 + q * 8);
        #pragma unroll
        for (int mt = 0; mt < 4; ++mt) {
            acc[mt][0] = __builtin_amdgcn_mfma_f32_16x16x32_bf16(a[mt], bf0[0][kk], acc[mt][0], 0, 0, 0);
            acc[mt][1] = __builtin_amdgcn_mfma_f32_16x16x32_bf16(a[mt], bf0[1][kk], acc[mt][1], 0, 0, 0);
        }
    }
    #pragma unroll
    for (int kk = 0; kk < 4; ++kk) {
        short8 a[4];
        #pragma unroll
        for (int mt = 0; mt < 4; ++mt)
            a[mt] = *(const short8*)(lxB + (mt * 16 + m16) * 136 + kk * 32 + q * 8);
        #pragma unroll
        for (int mt = 0; mt < 4; ++mt) {
            acc[mt][0] = __builtin_amdgcn_mfma_f32_16x16x32_bf16(a[mt], bf1[0][kk], acc[mt][0], 0, 0, 0);
            acc[mt][1] = __builtin_amdgcn_mfma_f32_16x16x32_bf16(a[mt], bf1[1][kk], acc[mt][1], 0, 0, 0);
        }
    }
    __syncthreads();   // MFMA reads done; smem reusable for C restage

    if (of32) {
        float* C = (float*)smem;   // 64 x 132 fp32 (33792 B)
        #pragma unroll
        for (int mt = 0; mt < 4; ++mt)
            #pragma unroll
            for (int r = 0; r < 4; ++r) {
                int rl = mt * 16 + q * 4 + r;
                int rr = node0 + rl;
                float e = (rr < N && ex) ? ex[rr] : 0.0f;
                #pragma unroll
                for (int nt = 0; nt < 2; ++nt) {
                    float v = acc[mt][nt][r];
                    if (relu) v = fmaxf(v, 0.0f);
                    C[rl * 132 + n_off + nt * 16 + m16] = v * e;
                }
            }
        __syncthreads();
        #pragma unroll
        for (int i = 0; i < 8; ++i) {
            int g = t + 256 * i;              // 64 rows x 32 float4
            int nd = g >> 5, k = g & 31;
            int rr = node0 + nd;
            if (rr < N)
                *(float4*)(of32 + (size_t)rr * 128 + k * 4) = *(const float4*)(C + nd * 132 + k * 4);
        }
    } else {
        #pragma unroll
        for (int mt = 0; mt < 4; ++mt)
            #pragma unroll
            for (int r = 0; r < 4; ++r) {
                int rl = mt * 16 + q * 4 + r;
                int rr = node0 + rl;
                float e = (rr < N && ex) ? ex[rr] : 0.0f;
                #pragma unroll
                for (int nt = 0; nt < 2; ++nt) {
                    float v = acc[mt][nt][r];
                    if (relu) v = fmaxf(v, 0.0f);
                    lxA[rl * 136 + n_off + nt * 16 + m16] = f2bf(v * e);
                }
            }
        __syncthreads();
        #pragma unroll
        for (int i = 0; i < 4; ++i) {
            int cidx = t + 256 * i;
            int nd = cidx >> 4, k = cidx & 15;
            int rr = node0 + nd;
            if (rr < N)
                *(uint4*)(obf + (size_t)rr * 128 + k * 8) = *(const uint4*)(lxA + nd * 136 + k * 8);
        }
    }
}

// ---------------- launch ----------------

extern "C" void kernel_launch(void* const* d_in, const int* in_sizes, int n_in,
                              void* d_out, int out_size, void* d_ws, size_t ws_size,
                              hipStream_t stream) {
    const float* attr = (const float*)d_in[0];
    const float* cc   = (const float*)d_in[1];
    const float* bl   = (const float*)d_in[2];
    const float* ex   = (const float*)d_in[3];
    const float* w_in = (const float*)d_in[4];
    const float* b_in = (const float*)d_in[5];
    const float* w1s  = (const float*)d_in[6];
    const float* b1s  = (const float*)d_in[7];
    const float* w1n  = (const float*)d_in[8];
    const float* b1n  = (const float*)d_in[9];
    const float* w2s  = (const float*)d_in[10];
    const float* b2s  = (const float*)d_in[11];
    const float* w2n  = (const float*)d_in[12];
    const float* b2n  = (const float*)d_in[13];
    const int*   eidx = (const int*)d_in[14];

    int N = in_sizes[3];
    int ATTR = in_sizes[0] / N;
    int E = in_sizes[14] / 2;
    int Npad = ((N + 63) / 64) * 64;
    int nchunk = (N + 511) / 512;                  // 98
    int ntilesE = (E + BTILE - 1) / BTILE;         // 391
    int gblk = Npad / 64;                          // 782

    char* ws = (char*)d_ws;
    size_t off = 0;
    auto alloc = [&](size_t bytes) -> char* {
        off = (off + 255) & ~(size_t)255;
        char* p = ws + off;
        off += bytes;
        return p;
    };
    unsigned short* x1 = (unsigned short*)alloc((size_t)Npad * 128 * 2);
    unsigned short* x2 = (unsigned short*)alloc((size_t)Npad * 128 * 2);
    int* colv        = (int*)alloc((size_t)nchunk * CHUNK_CAP * 4);
    unsigned* packed = (unsigned*)alloc((size_t)nchunk * CHUNK_CAP * 4);
    uint2* rows2     = (uint2*)alloc((size_t)N * 8);
    int* cursor      = (int*)alloc(132 * 4);       // cursor[128] + done @128
    unsigned short* wb = (unsigned short*)alloc((size_t)4 * 16384 * 2);
    float* biasf     = (float*)alloc(256 * 4);
    int* done        = cursor + 128;

    hipMemsetAsync(cursor, 0, 132 * sizeof(int), stream);

    // K1: bin | csr(spin) | prep | layer-0 GEMM
    front_fused<<<ntilesE + nchunk + NPREP + gblk, 256, 0, stream>>>(
        attr, cc, bl, ex, w_in, b_in, x1,
        eidx, cursor, done, packed, rows2, colv,
        w1s, w1n, w2s, w2n, b1s, b1n, b2s, b2n, wb, biasf,
        N, ATTR, E, ntilesE, nchunk);
    // K2: x2 = relu(x1 @ W1s^T + mean(x1) @ W1n^T + b1) * ex
    gemm_sage<<<gblk, 256, 0, stream>>>(x1, rows2, colv, wb, wb + 16384,
                                        biasf, ex, x2, (float*)nullptr, N, 1);
    // K3: out = (x2 @ W2s^T + mean(x2) @ W2n^T + b2) * ex   (fp32)
    gemm_sage<<<gblk, 256, 0, stream>>>(x2, rows2, colv, wb + 2 * 16384, wb + 3 * 16384,
                                        biasf + 128, ex, (unsigned short*)nullptr,
                                        (float*)d_out, N, 0);
}

// Round 4
// 236.712 us; speedup vs baseline: 1.4812x; 1.4812x over previous
//
#include <hip/hip_runtime.h>

typedef __attribute__((ext_vector_type(8))) short short8;
typedef __attribute__((ext_vector_type(4))) float floatx4;

__device__ inline unsigned short f2bf(float f) {
    unsigned u = __float_as_uint(f);
    u += 0x7fffu + ((u >> 16) & 1u);   // round-to-nearest-even
    return (unsigned short)(u >> 16);
}

// 512-node chunks: chunk = tgt>>9, 98 chunks for N=50000.
// packed word: (chunk<<25) | (src<<9) | (tgt&511)   [src < 65536]
#define CHUNK_CAP 12288   // mean E/98 = 8163, sigma ~90
#define BTILE 2048        // 391 tiles: short per-block chain, high parallelism
#define NPREP 256         // 4*16384/256 weight-convert blocks

// ============ K1: layer-0 GEMM | edge binning | weight prep (all independent) ============
// Block ranges: [0,gblk) gemm0, [gblk,gblk+ntilesE) bin, rest prep.
// No cross-block sync anywhere (R3 lesson: spin/fence poisons the whole kernel).

__global__ __launch_bounds__(256, 4) void gemm0_bin(
    const float* __restrict__ attr, const float* __restrict__ cc,
    const float* __restrict__ bl, const float* __restrict__ ex,
    const float* __restrict__ Wf, const float* __restrict__ bias0,
    unsigned short* __restrict__ x1,
    const int* __restrict__ e, int* __restrict__ cursor,
    unsigned* __restrict__ packed_out,
    const float* __restrict__ w1s, const float* __restrict__ w1n,
    const float* __restrict__ w2s, const float* __restrict__ w2n,
    const float* __restrict__ b1s, const float* __restrict__ b1n,
    const float* __restrict__ b2s, const float* __restrict__ b2n,
    unsigned short* __restrict__ wb, float* __restrict__ biasf,
    int N, int ATTR, int E, int ntilesE, int gblk) {
    __shared__ __align__(16) char smem[18432];   // bin: 8K+8K+2K; gemm0: 17408
    int t = threadIdx.x;
    int bid = blockIdx.x;

    if (bid >= gblk && bid < gblk + ntilesE) {
        // ---- edge binning: one 2048-edge tile into 128 chunk bins ----
        unsigned* buf  = (unsigned*)smem;
        unsigned* sbuf = buf + BTILE;
        int* hist  = (int*)(sbuf + BTILE);
        int* offs  = hist + 128;
        int* gbase = offs + 128;
        int* lcur  = gbase + 128;
        int e0 = (bid - gblk) * BTILE;
        int cnt = min(BTILE, E - e0);
        if (t < 128) hist[t] = 0;
        __syncthreads();
        for (int j = t; j < cnt; j += 256) {
            unsigned src = (unsigned)e[e0 + j];
            unsigned tgt = (unsigned)e[E + e0 + j];
            unsigned c = tgt >> 9;
            buf[j] = (c << 25) | (src << 9) | (tgt & 511u);
            atomicAdd(&hist[c], 1);
        }
        __syncthreads();
        if (t < 128) offs[t] = hist[t];
        __syncthreads();
        for (int o = 1; o < 128; o <<= 1) {
            int v = (t < 128 && t >= o) ? offs[t - o] : 0;
            __syncthreads();
            if (t < 128) offs[t] += v;
            __syncthreads();
        }
        if (t < 128) {
            int excl = offs[t] - hist[t];
            offs[t] = excl;
            lcur[t] = excl;
            gbase[t] = (hist[t] > 0) ? t * CHUNK_CAP + atomicAdd(&cursor[t], hist[t]) : 0;
        }
        __syncthreads();
        for (int j = t; j < cnt; j += 256) {
            unsigned v = buf[j];
            int c = v >> 25;
            int p = atomicAdd(&lcur[c], 1);
            sbuf[p] = v;
        }
        __syncthreads();
        // flat coalesced write-out: consecutive j -> consecutive dest within runs
        for (int j = t; j < cnt; j += 256) {
            unsigned v = sbuf[j];
            int c = v >> 25;
            packed_out[gbase[c] + (j - offs[c])] = v;
        }
        return;
    }

    if (bid >= gblk + ntilesE) {
        // ---- weight prep: w1s|w1n|w2s|w2n -> bf16, fused biases ----
        int pb = bid - gblk - ntilesE;
        int idx = pb * 256 + t;            // 0..65535
        int m = idx >> 14, j = idx & 16383;
        const float* src = (m == 0) ? w1s : (m == 1) ? w1n : (m == 2) ? w2s : w2n;
        wb[idx] = f2bf(src[j]);
        if (pb == 0 && t < 128) {
            biasf[t]       = b1s[t] + b1n[t];
            biasf[128 + t] = b2s[t] + b2n[t];
        }
        return;
    }

    // ---- layer-0 GEMM: x1 = relu(x0 @ W_in^T + b_in), x0 built in-register ----
    // (assumes IN = ATTR+3 = 128, fixed for this problem)
    unsigned short* lx = (unsigned short*)smem;   // 64 x 136 bf16 tile
    int lane = t & 63;
    int w = t >> 6;
    int node0 = bid * 64;
    int n_off = w * 32;
    int q = lane >> 4;
    int m16 = lane & 15;

    // B fragments: fp32 W_in -> bf16 in-register (64 KB, L2-resident)
    short8 bf[2][4];
    #pragma unroll
    for (int nt = 0; nt < 2; ++nt)
        #pragma unroll
        for (int kk = 0; kk < 4; ++kk) {
            const float* p = Wf + (n_off + nt * 16 + m16) * 128 + kk * 32 + q * 8;
            float4 aa = *(const float4*)p, bb = *(const float4*)(p + 4);
            short8 r;
            r[0] = (short)f2bf(aa.x); r[1] = (short)f2bf(aa.y);
            r[2] = (short)f2bf(aa.z); r[3] = (short)f2bf(aa.w);
            r[4] = (short)f2bf(bb.x); r[5] = (short)f2bf(bb.y);
            r[6] = (short)f2bf(bb.z); r[7] = (short)f2bf(bb.w);
            bf[nt][kk] = r;
        }

    floatx4 acc[4][2];
    #pragma unroll
    for (int nt = 0; nt < 2; ++nt) {
        float bv = bias0[n_off + nt * 16 + m16];
        floatx4 b4 = {bv, bv, bv, bv};
        #pragma unroll
        for (int mt = 0; mt < 4; ++mt) acc[mt][nt] = b4;
    }

    if (node0 + 64 > N) {   // tail block: zero tile first
        for (int i = t; i < 64 * 136; i += 256) lx[i] = 0;
        __syncthreads();
    }

    // attr -> bf16 tile, in-register convert (thread = (row, 4-col group))
    #pragma unroll
    for (int i = 0; i < 8; ++i) {
        int idx = t + 256 * i;            // 64 rows x 32 groups
        int nd = idx >> 5, g = idx & 31;
        int row = node0 + nd;
        int c0 = g * 4;
        if (row < N && c0 < ATTR) {
            if (c0 + 3 < ATTR) {
                float4 f = *(const float4*)(attr + (size_t)row * ATTR + c0);
                unsigned lo = (unsigned)f2bf(f.x) | ((unsigned)f2bf(f.y) << 16);
                unsigned hi = (unsigned)f2bf(f.z) | ((unsigned)f2bf(f.w) << 16);
                uint2 pk; pk.x = lo; pk.y = hi;
                *(uint2*)(lx + nd * 136 + c0) = pk;
            } else {
                for (int k = 0; k < 4; ++k) {
                    int cidx = c0 + k;
                    if (cidx < ATTR) lx[nd * 136 + cidx] = f2bf(attr[(size_t)row * ATTR + cidx]);
                }
            }
        }
    }
    // boundary cols ATTR..ATTR+2 from cc/bl/ex
    {
        int nd = t >> 2, ci = t & 3;
        int row = node0 + nd;
        if (ci < 3 && row < N) {
            float v = (ci == 0) ? cc[row] : (ci == 1) ? bl[row] : ex[row];
            lx[nd * 136 + ATTR + ci] = f2bf(v);
        }
    }
    __syncthreads();

    #pragma unroll
    for (int kk = 0; kk < 4; ++kk) {
        short8 a[4];
        #pragma unroll
        for (int mt = 0; mt < 4; ++mt)
            a[mt] = *(const short8*)(lx + (mt * 16 + m16) * 136 + kk * 32 + q * 8);
        #pragma unroll
        for (int mt = 0; mt < 4; ++mt) {
            acc[mt][0] = __builtin_amdgcn_mfma_f32_16x16x32_bf16(a[mt], bf[0][kk], acc[mt][0], 0, 0, 0);
            acc[mt][1] = __builtin_amdgcn_mfma_f32_16x16x32_bf16(a[mt], bf[1][kk], acc[mt][1], 0, 0, 0);
        }
    }

    // epilogue: relu -> LDS restage -> coalesced uint4 stores
    __syncthreads();
    #pragma unroll
    for (int mt = 0; mt < 4; ++mt)
        #pragma unroll
        for (int r = 0; r < 4; ++r) {
            int rl = mt * 16 + q * 4 + r;
            #pragma unroll
            for (int nt = 0; nt < 2; ++nt)
                lx[rl * 136 + n_off + nt * 16 + m16] = f2bf(fmaxf(acc[mt][nt][r], 0.0f));
        }
    __syncthreads();
    #pragma unroll
    for (int i = 0; i < 4; ++i) {
        int cidx = t + 256 * i;           // 64 rows x 16 chunks of 16B
        int nd = cidx >> 4, k = cidx & 15;
        int rr = node0 + nd;
        if (rr < N)
            *(uint4*)(x1 + (size_t)rr * 128 + k * 8) = *(const uint4*)(lx + nd * 136 + k * 8);
    }
}

// ============ K2: per-chunk CSR finalize (R2-proven, LDS-staged) ============

__global__ __launch_bounds__(256) void chunk_csr(const unsigned* __restrict__ packed,
                                                 const int* __restrict__ cursor,
                                                 uint2* __restrict__ rows2,
                                                 int* __restrict__ colv, int N) {
    __shared__ int hist[512], offs[512], lcnt[512], pp[256];
    __shared__ int sbuf[CHUNK_CAP];
    int c = blockIdx.x;
    int base = c * CHUNK_CAP;
    int cnt = cursor[c];
    int t = threadIdx.x;
    hist[t] = 0;
    hist[t + 256] = 0;
    __syncthreads();
    for (int j = t; j < cnt; j += 256)
        atomicAdd(&hist[packed[base + j] & 511u], 1);
    __syncthreads();
    int a0 = hist[2 * t], a1 = hist[2 * t + 1];
    pp[t] = a0 + a1;
    __syncthreads();
    for (int o = 1; o < 256; o <<= 1) {
        int v = (t >= o) ? pp[t - o] : 0;
        __syncthreads();
        pp[t] += v;
        __syncthreads();
    }
    int excl = pp[t] - (a0 + a1);
    offs[2 * t] = excl;
    offs[2 * t + 1] = excl + a0;
    lcnt[2 * t] = 0;
    lcnt[2 * t + 1] = 0;
    __syncthreads();
    for (int j = t; j < 512; j += 256) {
        int node = c * 512 + j;
        if (node < N) {
            uint2 r;
            r.x = base + offs[j];
            r.y = base + offs[j] + hist[j];
            rows2[node] = r;
        }
    }
    for (int j = t; j < cnt; j += 256) {
        unsigned v = packed[base + j];
        int node = v & 511u;
        int p = offs[node] + atomicAdd(&lcnt[node], 1);
        sbuf[p] = (v >> 9) & 0xFFFFu;
    }
    __syncthreads();
    for (int j = t; j < cnt; j += 256) colv[base + j] = sbuf[j];
}

// ============ segment mean: one wave per node (R0/R2-proven, untouched) ============

__global__ __launch_bounds__(256) void agg_mean(const unsigned short* __restrict__ x,
                                                const uint2* __restrict__ rows2,
                                                const int* __restrict__ colv,
                                                unsigned short* __restrict__ nm, int N) {
    int wid = (blockIdx.x * 256 + threadIdx.x) >> 6;
    int lane = threadIdx.x & 63;
    if (wid >= N) return;
    uint2 r = rows2[wid];
    int s0 = r.x, s1 = r.y;
    int deg = s1 - s0;
    int mn = deg < 64 ? deg : 64;
    int cvec = (lane < mn) ? colv[s0 + lane] : 0;
    int quarter = lane >> 4;
    int cl = (lane & 15) * 8;
    float a0 = 0.f, a1 = 0.f, a2 = 0.f, a3 = 0.f;
    float a4 = 0.f, a5 = 0.f, a6 = 0.f, a7 = 0.f;
    int lim = mn - 1;
    for (int j = 0; j < mn; j += 32) {
        uint4 v[8];
        #pragma unroll
        for (int u = 0; u < 8; ++u) {
            int ei = j + 4 * u + quarter;
            int idx = (ei <= lim) ? ei : lim;
            int s = __shfl(cvec, idx, 64);
            v[u] = *(const uint4*)(x + (size_t)s * 128 + cl);
        }
        #pragma unroll
        for (int u = 0; u < 8; ++u) {
            int ei = j + 4 * u + quarter;
            if (ei <= lim) {
                a0 += __uint_as_float(v[u].x << 16);
                a1 += __uint_as_float(v[u].x & 0xffff0000u);
                a2 += __uint_as_float(v[u].y << 16);
                a3 += __uint_as_float(v[u].y & 0xffff0000u);
                a4 += __uint_as_float(v[u].z << 16);
                a5 += __uint_as_float(v[u].z & 0xffff0000u);
                a6 += __uint_as_float(v[u].w << 16);
                a7 += __uint_as_float(v[u].w & 0xffff0000u);
            }
        }
    }
    for (int e = s0 + 64; e < s1; e += 4) {
        int ei = e + quarter;
        int idx = (ei < s1) ? ei : s1 - 1;
        int s = colv[idx];
        uint4 v = *(const uint4*)(x + (size_t)s * 128 + cl);
        if (ei < s1) {
            a0 += __uint_as_float(v.x << 16);
            a1 += __uint_as_float(v.x & 0xffff0000u);
            a2 += __uint_as_float(v.y << 16);
            a3 += __uint_as_float(v.y & 0xffff0000u);
            a4 += __uint_as_float(v.z << 16);
            a5 += __uint_as_float(v.z & 0xffff0000u);
            a6 += __uint_as_float(v.w << 16);
            a7 += __uint_as_float(v.w & 0xffff0000u);
        }
    }
    a0 += __shfl_xor(a0, 16, 64); a0 += __shfl_xor(a0, 32, 64);
    a1 += __shfl_xor(a1, 16, 64); a1 += __shfl_xor(a1, 32, 64);
    a2 += __shfl_xor(a2, 16, 64); a2 += __shfl_xor(a2, 32, 64);
    a3 += __shfl_xor(a3, 16, 64); a3 += __shfl_xor(a3, 32, 64);
    a4 += __shfl_xor(a4, 16, 64); a4 += __shfl_xor(a4, 32, 64);
    a5 += __shfl_xor(a5, 16, 64); a5 += __shfl_xor(a5, 32, 64);
    a6 += __shfl_xor(a6, 16, 64); a6 += __shfl_xor(a6, 32, 64);
    a7 += __shfl_xor(a7, 16, 64); a7 += __shfl_xor(a7, 32, 64);
    if (quarter == 0) {
        float inv = 1.0f / (float)(deg > 1 ? deg : 1);
        a0 *= inv; a1 *= inv; a2 *= inv; a3 *= inv;
        a4 *= inv; a5 *= inv; a6 *= inv; a7 *= inv;
        uint4 o;
        o.x = ((unsigned)f2bf(a1) << 16) | (unsigned)f2bf(a0);
        o.y = ((unsigned)f2bf(a3) << 16) | (unsigned)f2bf(a2);
        o.z = ((unsigned)f2bf(a5) << 16) | (unsigned)f2bf(a4);
        o.w = ((unsigned)f2bf(a7) << 16) | (unsigned)f2bf(a6);
        *(uint4*)(nm + (size_t)wid * 128 + cl) = o;
    }
}

// ============ 2-phase fused GEMM (R2 core + vectorized epilogues) ============

__global__ __launch_bounds__(256, 3) void gemm_fused(
    const unsigned short* __restrict__ X0, const unsigned short* __restrict__ X1,
    const unsigned short* __restrict__ W0, const unsigned short* __restrict__ W1,
    const float* __restrict__ bias, const float* __restrict__ ex,
    unsigned short* __restrict__ obf, float* __restrict__ of32,
    int N, int relu) {
    __shared__ __align__(16) unsigned short lx[64 * 136];   // 17408 B
    int tid = threadIdx.x;
    int lane = tid & 63;
    int w = tid >> 6;
    int node0 = blockIdx.x * 64;
    int n_off = w * 32;
    int q = lane >> 4;
    int m16 = lane & 15;

    short8 bf0[2][4], bf1[2][4];
    #pragma unroll
    for (int nt = 0; nt < 2; ++nt)
        #pragma unroll
        for (int kk = 0; kk < 4; ++kk) {
            bf0[nt][kk] = *(const short8*)(W0 + (n_off + nt * 16 + m16) * 128 + kk * 32 + q * 8);
            bf1[nt][kk] = *(const short8*)(W1 + (n_off + nt * 16 + m16) * 128 + kk * 32 + q * 8);
        }

    floatx4 acc[4][2];
    #pragma unroll
    for (int nt = 0; nt < 2; ++nt) {
        float bv = bias[n_off + nt * 16 + m16];
        floatx4 b4 = {bv, bv, bv, bv};
        #pragma unroll
        for (int mt = 0; mt < 4; ++mt) acc[mt][nt] = b4;
    }

    for (int ph = 0; ph < 2; ++ph) {
        const unsigned short* X = ph ? X1 : X0;
        for (int i = 0; i < 4; ++i) {
            int c = tid + 256 * i;
            int nd = c >> 4, ck = c & 15;
            short8 v = {0, 0, 0, 0, 0, 0, 0, 0};
            if (node0 + nd < N) v = *(const short8*)(X + (size_t)(node0 + nd) * 128 + ck * 8);
            *(short8*)(lx + nd * 136 + ck * 8) = v;
        }
        __syncthreads();
        #pragma unroll
        for (int kk = 0; kk < 4; ++kk) {
            short8 a[4];
            #pragma unroll
            for (int mt = 0; mt < 4; ++mt)
                a[mt] = *(const short8*)(lx + (mt * 16 + m16) * 136 + kk * 32 + q * 8);
            #pragma unroll
            for (int mt = 0; mt < 4; ++mt) {
                const short8* p0 = ph ? &bf1[0][kk] : &bf0[0][kk];
                const short8* p1 = ph ? &bf1[1][kk] : &bf0[1][kk];
                acc[mt][0] = __builtin_amdgcn_mfma_f32_16x16x32_bf16(a[mt], *p0, acc[mt][0], 0, 0, 0);
                acc[mt][1] = __builtin_amdgcn_mfma_f32_16x16x32_bf16(a[mt], *p1, acc[mt][1], 0, 0, 0);
            }
        }
        __syncthreads();   // also releases lx for epilogue reuse after ph=1
    }

    if (obf) {
        // bf16 out: restage in lx, coalesced uint4 stores
        #pragma unroll
        for (int mt = 0; mt < 4; ++mt)
            #pragma unroll
            for (int r = 0; r < 4; ++r) {
                int rl = mt * 16 + q * 4 + r;
                int rr = node0 + rl;
                float e = (rr < N) ? ex[rr] : 0.0f;
                #pragma unroll
                for (int nt = 0; nt < 2; ++nt) {
                    float v = acc[mt][nt][r];
                    if (relu) v = fmaxf(v, 0.0f);
                    lx[rl * 136 + n_off + nt * 16 + m16] = f2bf(v * e);
                }
            }
        __syncthreads();
        #pragma unroll
        for (int i = 0; i < 4; ++i) {
            int cidx = tid + 256 * i;
            int nd = cidx >> 4, k = cidx & 15;
            int rr = node0 + nd;
            if (rr < N)
                *(uint4*)(obf + (size_t)rr * 128 + k * 8) = *(const uint4*)(lx + nd * 136 + k * 8);
        }
    } else {
        // fp32 out: two half-column passes through lx (64 x 66 fp32 = 16.9 KB)
        float* C = (float*)lx;
        #pragma unroll
        for (int pass = 0; pass < 2; ++pass) {
            if ((w >> 1) == pass) {   // waves whose cols fall in [pass*64, pass*64+64)
                #pragma unroll
                for (int mt = 0; mt < 4; ++mt)
                    #pragma unroll
                    for (int r = 0; r < 4; ++r) {
                        int rl = mt * 16 + q * 4 + r;
                        int rr = node0 + rl;
                        float e = (rr < N) ? ex[rr] : 0.0f;
                        #pragma unroll
                        for (int nt = 0; nt < 2; ++nt) {
                            float v = acc[mt][nt][r];
                            if (relu) v = fmaxf(v, 0.0f);
                            int colL = (w & 1) * 32 + nt * 16 + m16;
                            C[rl * 66 + colL] = v * e;
                        }
                    }
            }
            __syncthreads();
            #pragma unroll
            for (int i = 0; i < 4; ++i) {
                int g = tid + 256 * i;        // 64 rows x 16 float4 (64 cols)
                int nd = g >> 4, k = g & 15;
                int rr = node0 + nd;
                if (rr < N)
                    *(float4*)(of32 + (size_t)rr * 128 + pass * 64 + k * 4) =
                        *(const float4*)(C + nd * 66 + k * 4);
            }
            __syncthreads();
        }
    }
}

// ---------------- launch ----------------

extern "C" void kernel_launch(void* const* d_in, const int* in_sizes, int n_in,
                              void* d_out, int out_size, void* d_ws, size_t ws_size,
                              hipStream_t stream) {
    const float* attr = (const float*)d_in[0];
    const float* cc   = (const float*)d_in[1];
    const float* bl   = (const float*)d_in[2];
    const float* ex   = (const float*)d_in[3];
    const float* w_in = (const float*)d_in[4];
    const float* b_in = (const float*)d_in[5];
    const float* w1s  = (const float*)d_in[6];
    const float* b1s  = (const float*)d_in[7];
    const float* w1n  = (const float*)d_in[8];
    const float* b1n  = (const float*)d_in[9];
    const float* w2s  = (const float*)d_in[10];
    const float* b2s  = (const float*)d_in[11];
    const float* w2n  = (const float*)d_in[12];
    const float* b2n  = (const float*)d_in[13];
    const int*   eidx = (const int*)d_in[14];

    int N = in_sizes[3];
    int ATTR = in_sizes[0] / N;
    int E = in_sizes[14] / 2;
    int Npad = ((N + 63) / 64) * 64;
    int nchunk = (N + 511) / 512;                  // 98
    int ntilesE = (E + BTILE - 1) / BTILE;         // 391
    int gblk = Npad / 64;                          // 782

    char* ws = (char*)d_ws;
    size_t off = 0;
    auto alloc = [&](size_t bytes) -> char* {
        off = (off + 255) & ~(size_t)255;
        char* p = ws + off;
        off += bytes;
        return p;
    };
    unsigned short* x1 = (unsigned short*)alloc((size_t)Npad * 128 * 2);
    unsigned short* x2 = (unsigned short*)alloc((size_t)Npad * 128 * 2);
    unsigned short* nm = (unsigned short*)alloc((size_t)Npad * 128 * 2);
    int* colv        = (int*)alloc((size_t)nchunk * CHUNK_CAP * 4);
    unsigned* packed = (unsigned*)alloc((size_t)nchunk * CHUNK_CAP * 4);
    uint2* rows2     = (uint2*)alloc((size_t)N * 8);
    int* cursor      = (int*)alloc(128 * 4);
    unsigned short* wb = (unsigned short*)alloc((size_t)4 * 16384 * 2);
    float* biasf     = (float*)alloc(256 * 4);

    hipMemsetAsync(cursor, 0, 128 * sizeof(int), stream);

    // K1: layer-0 GEMM | edge binning | weight prep
    gemm0_bin<<<gblk + ntilesE + NPREP, 256, 0, stream>>>(
        attr, cc, bl, ex, w_in, b_in, x1,
        eidx, cursor, packed,
        w1s, w1n, w2s, w2n, b1s, b1n, b2s, b2n, wb, biasf,
        N, ATTR, E, ntilesE, gblk);
    // K2: CSR finalize
    chunk_csr<<<nchunk, 256, 0, stream>>>(packed, cursor, rows2, colv, N);
    // K3: nm1 = segment_mean(x1)
    agg_mean<<<(N + 3) / 4, 256, 0, stream>>>(x1, rows2, colv, nm, N);
    // K4: x2 = relu(x1 @ W1s^T + nm1 @ W1n^T + b1) * ex
    gemm_fused<<<gblk, 256, 0, stream>>>(x1, nm, wb, wb + 16384,
                                         biasf, ex, x2, (float*)nullptr, N, 1);
    // K5: nm2 = segment_mean(x2)
    agg_mean<<<(N + 3) / 4, 256, 0, stream>>>(x2, rows2, colv, nm, N);
    // K6: out = (x2 @ W2s^T + nm2 @ W2n^T + b2) * ex   (fp32)
    gemm_fused<<<gblk, 256, 0, stream>>>(x2, nm, wb + 2 * 16384, wb + 3 * 16384,
                                         biasf + 128, ex, (unsigned short*)nullptr,
                                         (float*)d_out, N, 0);
}

// Round 5
// 219.343 us; speedup vs baseline: 1.5985x; 1.0792x over previous
//
#include <hip/hip_runtime.h>

typedef __attribute__((ext_vector_type(8))) short short8;
typedef __attribute__((ext_vector_type(4))) float floatx4;

__device__ inline unsigned short f2bf(float f) {
    unsigned u = __float_as_uint(f);
    u += 0x7fffu + ((u >> 16) & 1u);   // round-to-nearest-even
    return (unsigned short)(u >> 16);
}

// 512-node chunks: chunk = tgt>>9, 98 chunks for N=50000.
// packed word: (chunk<<25) | (src<<9) | (tgt&511)   [src < 65536]
#define CHUNK_CAP 12288   // mean E/98 = 8163, sigma ~90
#define BTILE 2048        // 391 tiles: short per-block chain, high parallelism
#define NPREP 256         // 4*16384/256 weight-convert blocks

// ============ K1: layer-0 GEMM | edge binning | weight prep (all independent) ============
// No cross-block sync anywhere (R3 lesson: spin/fence poisons the whole kernel).

__global__ __launch_bounds__(256, 4) void gemm0_bin(
    const float* __restrict__ attr, const float* __restrict__ cc,
    const float* __restrict__ bl, const float* __restrict__ ex,
    const float* __restrict__ Wf, const float* __restrict__ bias0,
    unsigned short* __restrict__ x1,
    const int* __restrict__ e, int* __restrict__ cursor,
    unsigned* __restrict__ packed_out,
    const float* __restrict__ w1s, const float* __restrict__ w1n,
    const float* __restrict__ w2s, const float* __restrict__ w2n,
    const float* __restrict__ b1s, const float* __restrict__ b1n,
    const float* __restrict__ b2s, const float* __restrict__ b2n,
    unsigned short* __restrict__ wb, float* __restrict__ biasf,
    int N, int ATTR, int E, int ntilesE, int gblk) {
    __shared__ __align__(16) char smem[18432];   // bin: 8K+8K+2K; gemm0: 17408
    int t = threadIdx.x;
    int bid = blockIdx.x;

    if (bid >= gblk && bid < gblk + ntilesE) {
        // ---- edge binning: one 2048-edge tile into 128 chunk bins ----
        unsigned* buf  = (unsigned*)smem;
        unsigned* sbuf = buf + BTILE;
        int* hist  = (int*)(sbuf + BTILE);
        int* offs  = hist + 128;
        int* gbase = offs + 128;
        int* lcur  = gbase + 128;
        int e0 = (bid - gblk) * BTILE;
        int cnt = min(BTILE, E - e0);
        if (t < 128) hist[t] = 0;
        __syncthreads();
        for (int j = t; j < cnt; j += 256) {
            unsigned src = (unsigned)e[e0 + j];
            unsigned tgt = (unsigned)e[E + e0 + j];
            unsigned c = tgt >> 9;
            buf[j] = (c << 25) | (src << 9) | (tgt & 511u);
            atomicAdd(&hist[c], 1);
        }
        __syncthreads();
        if (t < 128) offs[t] = hist[t];
        __syncthreads();
        for (int o = 1; o < 128; o <<= 1) {
            int v = (t < 128 && t >= o) ? offs[t - o] : 0;
            __syncthreads();
            if (t < 128) offs[t] += v;
            __syncthreads();
        }
        if (t < 128) {
            int excl = offs[t] - hist[t];
            offs[t] = excl;
            lcur[t] = excl;
            gbase[t] = (hist[t] > 0) ? t * CHUNK_CAP + atomicAdd(&cursor[t], hist[t]) : 0;
        }
        __syncthreads();
        for (int j = t; j < cnt; j += 256) {
            unsigned v = buf[j];
            int c = v >> 25;
            int p = atomicAdd(&lcur[c], 1);
            sbuf[p] = v;
        }
        __syncthreads();
        for (int j = t; j < cnt; j += 256) {
            unsigned v = sbuf[j];
            int c = v >> 25;
            packed_out[gbase[c] + (j - offs[c])] = v;
        }
        return;
    }

    if (bid >= gblk + ntilesE) {
        // ---- weight prep: w1s|w1n|w2s|w2n -> bf16, fused biases ----
        int pb = bid - gblk - ntilesE;
        int idx = pb * 256 + t;            // 0..65535
        int m = idx >> 14, j = idx & 16383;
        const float* src = (m == 0) ? w1s : (m == 1) ? w1n : (m == 2) ? w2s : w2n;
        wb[idx] = f2bf(src[j]);
        if (pb == 0 && t < 128) {
            biasf[t]       = b1s[t] + b1n[t];
            biasf[128 + t] = b2s[t] + b2n[t];
        }
        return;
    }

    // ---- layer-0 GEMM: x1 = relu(x0 @ W_in^T + b_in), x0 built in-register ----
    // (assumes IN = ATTR+3 = 128, fixed for this problem)
    unsigned short* lx = (unsigned short*)smem;   // 64 x 136 bf16 tile
    int lane = t & 63;
    int w = t >> 6;
    int node0 = bid * 64;
    int n_off = w * 32;
    int q = lane >> 4;
    int m16 = lane & 15;

    // B fragments: fp32 W_in -> bf16 in-register (64 KB, L2-resident)
    short8 bf[2][4];
    #pragma unroll
    for (int nt = 0; nt < 2; ++nt)
        #pragma unroll
        for (int kk = 0; kk < 4; ++kk) {
            const float* p = Wf + (n_off + nt * 16 + m16) * 128 + kk * 32 + q * 8;
            float4 aa = *(const float4*)p, bb = *(const float4*)(p + 4);
            short8 r;
            r[0] = (short)f2bf(aa.x); r[1] = (short)f2bf(aa.y);
            r[2] = (short)f2bf(aa.z); r[3] = (short)f2bf(aa.w);
            r[4] = (short)f2bf(bb.x); r[5] = (short)f2bf(bb.y);
            r[6] = (short)f2bf(bb.z); r[7] = (short)f2bf(bb.w);
            bf[nt][kk] = r;
        }

    floatx4 acc[4][2];
    #pragma unroll
    for (int nt = 0; nt < 2; ++nt) {
        float bv = bias0[n_off + nt * 16 + m16];
        floatx4 b4 = {bv, bv, bv, bv};
        #pragma unroll
        for (int mt = 0; mt < 4; ++mt) acc[mt][nt] = b4;
    }

    if (node0 + 64 > N) {   // tail block: zero tile first
        for (int i = t; i < 64 * 136; i += 256) lx[i] = 0;
        __syncthreads();
    }

    // attr -> bf16 tile, in-register convert (thread = (row, 4-col group))
    #pragma unroll
    for (int i = 0; i < 8; ++i) {
        int idx = t + 256 * i;            // 64 rows x 32 groups
        int nd = idx >> 5, g = idx & 31;
        int row = node0 + nd;
        int c0 = g * 4;
        if (row < N && c0 < ATTR) {
            if (c0 + 3 < ATTR) {
                float4 f = *(const float4*)(attr + (size_t)row * ATTR + c0);
                unsigned lo = (unsigned)f2bf(f.x) | ((unsigned)f2bf(f.y) << 16);
                unsigned hi = (unsigned)f2bf(f.z) | ((unsigned)f2bf(f.w) << 16);
                uint2 pk; pk.x = lo; pk.y = hi;
                *(uint2*)(lx + nd * 136 + c0) = pk;
            } else {
                for (int k = 0; k < 4; ++k) {
                    int cidx = c0 + k;
                    if (cidx < ATTR) lx[nd * 136 + cidx] = f2bf(attr[(size_t)row * ATTR + cidx]);
                }
            }
        }
    }
    // boundary cols ATTR..ATTR+2 from cc/bl/ex
    {
        int nd = t >> 2, ci = t & 3;
        int row = node0 + nd;
        if (ci < 3 && row < N) {
            float v = (ci == 0) ? cc[row] : (ci == 1) ? bl[row] : ex[row];
            lx[nd * 136 + ATTR + ci] = f2bf(v);
        }
    }
    __syncthreads();

    #pragma unroll
    for (int kk = 0; kk < 4; ++kk) {
        short8 a[4];
        #pragma unroll
        for (int mt = 0; mt < 4; ++mt)
            a[mt] = *(const short8*)(lx + (mt * 16 + m16) * 136 + kk * 32 + q * 8);
        #pragma unroll
        for (int mt = 0; mt < 4; ++mt) {
            acc[mt][0] = __builtin_amdgcn_mfma_f32_16x16x32_bf16(a[mt], bf[0][kk], acc[mt][0], 0, 0, 0);
            acc[mt][1] = __builtin_amdgcn_mfma_f32_16x16x32_bf16(a[mt], bf[1][kk], acc[mt][1], 0, 0, 0);
        }
    }

    // epilogue: relu -> LDS restage -> coalesced uint4 stores
    __syncthreads();
    #pragma unroll
    for (int mt = 0; mt < 4; ++mt)
        #pragma unroll
        for (int r = 0; r < 4; ++r) {
            int rl = mt * 16 + q * 4 + r;
            #pragma unroll
            for (int nt = 0; nt < 2; ++nt)
                lx[rl * 136 + n_off + nt * 16 + m16] = f2bf(fmaxf(acc[mt][nt][r], 0.0f));
        }
    __syncthreads();
    #pragma unroll
    for (int i = 0; i < 4; ++i) {
        int cidx = t + 256 * i;           // 64 rows x 16 chunks of 16B
        int nd = cidx >> 4, k = cidx & 15;
        int rr = node0 + nd;
        if (rr < N)
            *(uint4*)(x1 + (size_t)rr * 128 + k * 8) = *(const uint4*)(lx + nd * 136 + k * 8);
    }
}

// ============ K2: per-chunk CSR finalize (512 threads: half the serial passes) ============

__global__ __launch_bounds__(512) void chunk_csr(const unsigned* __restrict__ packed,
                                                 const int* __restrict__ cursor,
                                                 uint2* __restrict__ rows2,
                                                 int* __restrict__ colv, int N) {
    __shared__ int hist[512], offs[512], lcnt[512];
    __shared__ int sbuf[CHUNK_CAP];
    int c = blockIdx.x;
    int base = c * CHUNK_CAP;
    int cnt = cursor[c];
    int t = threadIdx.x;
    hist[t] = 0;
    __syncthreads();
    for (int j = t; j < cnt; j += 512)
        atomicAdd(&hist[packed[base + j] & 511u], 1);
    __syncthreads();
    offs[t] = hist[t];
    __syncthreads();
    for (int o = 1; o < 512; o <<= 1) {
        int v = (t >= o) ? offs[t - o] : 0;
        __syncthreads();
        offs[t] += v;
        __syncthreads();
    }
    int excl = offs[t] - hist[t];
    int node = c * 512 + t;
    if (node < N) {
        uint2 r;
        r.x = base + excl;
        r.y = base + excl + hist[t];
        rows2[node] = r;
    }
    offs[t] = excl;
    lcnt[t] = 0;
    __syncthreads();
    for (int j = t; j < cnt; j += 512) {
        unsigned v = packed[base + j];
        int nd = v & 511u;
        int p = offs[nd] + atomicAdd(&lcnt[nd], 1);
        sbuf[p] = (v >> 9) & 0xFFFFu;
    }
    __syncthreads();
    for (int j = t; j < cnt; j += 512) colv[base + j] = sbuf[j];
}

// ============ segment mean: one wave per node, PREDICATED loads ============
// Load guard (ei<=lim) is quarter-uniform -> exec-masked load, no memory request
// for masked quarters: halves gather traffic vs clamped-duplicate loads.
// Accumulation order unchanged (bit-exact vs R4).

__global__ __launch_bounds__(256) void agg_mean(const unsigned short* __restrict__ x,
                                                const uint2* __restrict__ rows2,
                                                const int* __restrict__ colv,
                                                unsigned short* __restrict__ nm, int N) {
    int wid = (blockIdx.x * 256 + threadIdx.x) >> 6;
    int lane = threadIdx.x & 63;
    if (wid >= N) return;
    uint2 r = rows2[wid];
    int s0 = r.x, s1 = r.y;
    int deg = s1 - s0;
    int mn = deg < 64 ? deg : 64;
    int cvec = (lane < mn) ? colv[s0 + lane] : 0;
    int quarter = lane >> 4;
    int cl = (lane & 15) * 8;
    float a0 = 0.f, a1 = 0.f, a2 = 0.f, a3 = 0.f;
    float a4 = 0.f, a5 = 0.f, a6 = 0.f, a7 = 0.f;
    int lim = mn - 1;
    for (int j = 0; j < mn; j += 32) {
        uint4 v[8];
        #pragma unroll
        for (int u = 0; u < 8; ++u) {
            int ei = j + 4 * u + quarter;
            int s = __shfl(cvec, (ei <= lim) ? ei : lim, 64);
            if (ei <= lim)
                v[u] = *(const uint4*)(x + (size_t)s * 128 + cl);
        }
        #pragma unroll
        for (int u = 0; u < 8; ++u) {
            int ei = j + 4 * u + quarter;
            if (ei <= lim) {
                a0 += __uint_as_float(v[u].x << 16);
                a1 += __uint_as_float(v[u].x & 0xffff0000u);
                a2 += __uint_as_float(v[u].y << 16);
                a3 += __uint_as_float(v[u].y & 0xffff0000u);
                a4 += __uint_as_float(v[u].z << 16);
                a5 += __uint_as_float(v[u].z & 0xffff0000u);
                a6 += __uint_as_float(v[u].w << 16);
                a7 += __uint_as_float(v[u].w & 0xffff0000u);
            }
        }
    }
    for (int e = s0 + 64; e < s1; e += 4) {
        int ei = e + quarter;
        int idx = (ei < s1) ? ei : s1 - 1;
        int s = colv[idx];
        if (ei < s1) {
            uint4 v = *(const uint4*)(x + (size_t)s * 128 + cl);
            a0 += __uint_as_float(v.x << 16);
            a1 += __uint_as_float(v.x & 0xffff0000u);
            a2 += __uint_as_float(v.y << 16);
            a3 += __uint_as_float(v.y & 0xffff0000u);
            a4 += __uint_as_float(v.z << 16);
            a5 += __uint_as_float(v.z & 0xffff0000u);
            a6 += __uint_as_float(v.w << 16);
            a7 += __uint_as_float(v.w & 0xffff0000u);
        }
    }
    a0 += __shfl_xor(a0, 16, 64); a0 += __shfl_xor(a0, 32, 64);
    a1 += __shfl_xor(a1, 16, 64); a1 += __shfl_xor(a1, 32, 64);
    a2 += __shfl_xor(a2, 16, 64); a2 += __shfl_xor(a2, 32, 64);
    a3 += __shfl_xor(a3, 16, 64); a3 += __shfl_xor(a3, 32, 64);
    a4 += __shfl_xor(a4, 16, 64); a4 += __shfl_xor(a4, 32, 64);
    a5 += __shfl_xor(a5, 16, 64); a5 += __shfl_xor(a5, 32, 64);
    a6 += __shfl_xor(a6, 16, 64); a6 += __shfl_xor(a6, 32, 64);
    a7 += __shfl_xor(a7, 16, 64); a7 += __shfl_xor(a7, 32, 64);
    if (quarter == 0) {
        float inv = 1.0f / (float)(deg > 1 ? deg : 1);
        a0 *= inv; a1 *= inv; a2 *= inv; a3 *= inv;
        a4 *= inv; a5 *= inv; a6 *= inv; a7 *= inv;
        uint4 o;
        o.x = ((unsigned)f2bf(a1) << 16) | (unsigned)f2bf(a0);
        o.y = ((unsigned)f2bf(a3) << 16) | (unsigned)f2bf(a2);
        o.z = ((unsigned)f2bf(a5) << 16) | (unsigned)f2bf(a4);
        o.w = ((unsigned)f2bf(a7) << 16) | (unsigned)f2bf(a6);
        *(uint4*)(nm + (size_t)wid * 128 + cl) = o;
    }
}

// ============ 2-phase fused GEMM: both X tiles staged upfront (2 barriers) ============

__global__ __launch_bounds__(256, 3) void gemm_fused(
    const unsigned short* __restrict__ X0, const unsigned short* __restrict__ X1,
    const unsigned short* __restrict__ W0, const unsigned short* __restrict__ W1,
    const float* __restrict__ bias, const float* __restrict__ ex,
    unsigned short* __restrict__ obf, float* __restrict__ of32,
    int N, int relu) {
    __shared__ __align__(16) unsigned short lx[2 * 64 * 136];   // 34816 B
    int tid = threadIdx.x;
    int lane = tid & 63;
    int w = tid >> 6;
    int node0 = blockIdx.x * 64;
    int n_off = w * 32;
    int q = lane >> 4;
    int m16 = lane & 15;

    // stage BOTH X tiles first: 8 global loads in flight immediately
    #pragma unroll
    for (int ph = 0; ph < 2; ++ph) {
        const unsigned short* X = ph ? X1 : X0;
        unsigned short* L = lx + ph * 64 * 136;
        #pragma unroll
        for (int i = 0; i < 4; ++i) {
            int c = tid + 256 * i;
            int nd = c >> 4, ck = c & 15;
            short8 v = {0, 0, 0, 0, 0, 0, 0, 0};
            if (node0 + nd < N) v = *(const short8*)(X + (size_t)(node0 + nd) * 128 + ck * 8);
            *(short8*)(L + nd * 136 + ck * 8) = v;
        }
    }

    short8 bf0[2][4], bf1[2][4];
    #pragma unroll
    for (int nt = 0; nt < 2; ++nt)
        #pragma unroll
        for (int kk = 0; kk < 4; ++kk) {
            bf0[nt][kk] = *(const short8*)(W0 + (n_off + nt * 16 + m16) * 128 + kk * 32 + q * 8);
            bf1[nt][kk] = *(const short8*)(W1 + (n_off + nt * 16 + m16) * 128 + kk * 32 + q * 8);
        }

    floatx4 acc[4][2];
    #pragma unroll
    for (int nt = 0; nt < 2; ++nt) {
        float bv = bias[n_off + nt * 16 + m16];
        floatx4 b4 = {bv, bv, bv, bv};
        #pragma unroll
        for (int mt = 0; mt < 4; ++mt) acc[mt][nt] = b4;
    }
    __syncthreads();

    #pragma unroll
    for (int ph = 0; ph < 2; ++ph) {
        const unsigned short* L = lx + ph * 64 * 136;
        #pragma unroll
        for (int kk = 0; kk < 4; ++kk) {
            short8 a[4];
            #pragma unroll
            for (int mt = 0; mt < 4; ++mt)
                a[mt] = *(const short8*)(L + (mt * 16 + m16) * 136 + kk * 32 + q * 8);
            #pragma unroll
            for (int mt = 0; mt < 4; ++mt) {
                const short8* p0 = ph ? &bf1[0][kk] : &bf0[0][kk];
                const short8* p1 = ph ? &bf1[1][kk] : &bf0[1][kk];
                acc[mt][0] = __builtin_amdgcn_mfma_f32_16x16x32_bf16(a[mt], *p0, acc[mt][0], 0, 0, 0);
                acc[mt][1] = __builtin_amdgcn_mfma_f32_16x16x32_bf16(a[mt], *p1, acc[mt][1], 0, 0, 0);
            }
        }
    }
    __syncthreads();   // MFMA reads done; lx reusable for epilogue

    if (obf) {
        // bf16 out: restage in lx, coalesced uint4 stores
        #pragma unroll
        for (int mt = 0; mt < 4; ++mt)
            #pragma unroll
            for (int r = 0; r < 4; ++r) {
                int rl = mt * 16 + q * 4 + r;
                int rr = node0 + rl;
                float e = (rr < N) ? ex[rr] : 0.0f;
                #pragma unroll
                for (int nt = 0; nt < 2; ++nt) {
                    float v = acc[mt][nt][r];
                    if (relu) v = fmaxf(v, 0.0f);
                    lx[rl * 136 + n_off + nt * 16 + m16] = f2bf(v * e);
                }
            }
        __syncthreads();
        #pragma unroll
        for (int i = 0; i < 4; ++i) {
            int cidx = tid + 256 * i;
            int nd = cidx >> 4, k = cidx & 15;
            int rr = node0 + nd;
            if (rr < N)
                *(uint4*)(obf + (size_t)rr * 128 + k * 8) = *(const uint4*)(lx + nd * 136 + k * 8);
        }
    } else {
        // fp32 out: full 64 x 132 fp32 restage (33792 B fits in lx)
        float* C = (float*)lx;
        #pragma unroll
        for (int mt = 0; mt < 4; ++mt)
            #pragma unroll
            for (int r = 0; r < 4; ++r) {
                int rl = mt * 16 + q * 4 + r;
                int rr = node0 + rl;
                float e = (rr < N) ? ex[rr] : 0.0f;
                #pragma unroll
                for (int nt = 0; nt < 2; ++nt) {
                    float v = acc[mt][nt][r];
                    if (relu) v = fmaxf(v, 0.0f);
                    C[rl * 132 + n_off + nt * 16 + m16] = v * e;
                }
            }
        __syncthreads();
        #pragma unroll
        for (int i = 0; i < 8; ++i) {
            int g = tid + 256 * i;            // 64 rows x 32 float4
            int nd = g >> 5, k = g & 31;
            int rr = node0 + nd;
            if (rr < N)
                *(float4*)(of32 + (size_t)rr * 128 + k * 4) = *(const float4*)(C + nd * 132 + k * 4);
        }
    }
}

// ---------------- launch ----------------

extern "C" void kernel_launch(void* const* d_in, const int* in_sizes, int n_in,
                              void* d_out, int out_size, void* d_ws, size_t ws_size,
                              hipStream_t stream) {
    const float* attr = (const float*)d_in[0];
    const float* cc   = (const float*)d_in[1];
    const float* bl   = (const float*)d_in[2];
    const float* ex   = (const float*)d_in[3];
    const float* w_in = (const float*)d_in[4];
    const float* b_in = (const float*)d_in[5];
    const float* w1s  = (const float*)d_in[6];
    const float* b1s  = (const float*)d_in[7];
    const float* w1n  = (const float*)d_in[8];
    const float* b1n  = (const float*)d_in[9];
    const float* w2s  = (const float*)d_in[10];
    const float* b2s  = (const float*)d_in[11];
    const float* w2n  = (const float*)d_in[12];
    const float* b2n  = (const float*)d_in[13];
    const int*   eidx = (const int*)d_in[14];

    int N = in_sizes[3];
    int ATTR = in_sizes[0] / N;
    int E = in_sizes[14] / 2;
    int Npad = ((N + 63) / 64) * 64;
    int nchunk = (N + 511) / 512;                  // 98
    int ntilesE = (E + BTILE - 1) / BTILE;         // 391
    int gblk = Npad / 64;                          // 782

    char* ws = (char*)d_ws;
    size_t off = 0;
    auto alloc = [&](size_t bytes) -> char* {
        off = (off + 255) & ~(size_t)255;
        char* p = ws + off;
        off += bytes;
        return p;
    };
    unsigned short* x1 = (unsigned short*)alloc((size_t)Npad * 128 * 2);
    unsigned short* x2 = (unsigned short*)alloc((size_t)Npad * 128 * 2);
    unsigned short* nm = (unsigned short*)alloc((size_t)Npad * 128 * 2);
    int* colv        = (int*)alloc((size_t)nchunk * CHUNK_CAP * 4);
    unsigned* packed = (unsigned*)alloc((size_t)nchunk * CHUNK_CAP * 4);
    uint2* rows2     = (uint2*)alloc((size_t)N * 8);
    int* cursor      = (int*)alloc(128 * 4);
    unsigned short* wb = (unsigned short*)alloc((size_t)4 * 16384 * 2);
    float* biasf     = (float*)alloc(256 * 4);

    hipMemsetAsync(cursor, 0, 128 * sizeof(int), stream);

    // K1: layer-0 GEMM | edge binning | weight prep
    gemm0_bin<<<gblk + ntilesE + NPREP, 256, 0, stream>>>(
        attr, cc, bl, ex, w_in, b_in, x1,
        eidx, cursor, packed,
        w1s, w1n, w2s, w2n, b1s, b1n, b2s, b2n, wb, biasf,
        N, ATTR, E, ntilesE, gblk);
    // K2: CSR finalize
    chunk_csr<<<nchunk, 512, 0, stream>>>(packed, cursor, rows2, colv, N);
    // K3: nm1 = segment_mean(x1)
    agg_mean<<<(N + 3) / 4, 256, 0, stream>>>(x1, rows2, colv, nm, N);
    // K4: x2 = relu(x1 @ W1s^T + nm1 @ W1n^T + b1) * ex
    gemm_fused<<<gblk, 256, 0, stream>>>(x1, nm, wb, wb + 16384,
                                         biasf, ex, x2, (float*)nullptr, N, 1);
    // K5: nm2 = segment_mean(x2)
    agg_mean<<<(N + 3) / 4, 256, 0, stream>>>(x2, rows2, colv, nm, N);
    // K6: out = (x2 @ W2s^T + nm2 @ W2n^T + b2) * ex   (fp32)
    gemm_fused<<<gblk, 256, 0, stream>>>(x2, nm, wb + 2 * 16384, wb + 3 * 16384,
                                         biasf + 128, ex, (unsigned short*)nullptr,
                                         (float*)d_out, N, 0);
}